// Round 1
// baseline (728.814 us; speedup 1.0000x reference)
//
#include <hip/hip_runtime.h>
#include <math.h>

// Problem constants (x: [32,64,64,64] f32, embedding: [64,1024] f32)
#define NPIX   131072     // 32*64*64
#define DDIM   64
#define KCODE  1024
#define BETA   0.25f

// d_out layout (float32), in reference return order:
//   [0, 8388608)                quantized_st
//   [8388608]                   loss
//   [8388609]                   perplexity
//   [8388610, 142606338)        encodings one-hot  (NOTE: only 8B-aligned!)
//   [142606338, 142737410)      encoding_indices (stored as float values)
#define Q_OFF    0
#define LOSS_OFF 8388608
#define PERP_OFF 8388609
#define ENC_OFF  8388610
#define IDX_OFF  142606338

// ws layout (bytes):
//   [0, 32768)        loss partials float[8192]
//   [32768, 36864)    hist int[1024]          (memset to 0 each call)
//   [36864, 40960)    norms float[1024]
//   [40960, 303104)   embT float[1024*64]     (embT[k][d] = emb[d][k])

// ---------- transpose embedding [D][K] -> [K][D] ----------
__global__ void vq_transpose(const float* __restrict__ emb, float* __restrict__ embT) {
    int i = blockIdx.x * 256 + threadIdx.x;   // over 65536
    int d = i >> 10;
    int k = i & 1023;
    embT[k * DDIM + d] = emb[i];
}

// ---------- per-code squared norms ----------
__global__ void vq_norms(const float* __restrict__ emb, float* __restrict__ norms) {
    int k = blockIdx.x * 256 + threadIdx.x;   // over 1024
    float s = 0.f;
    #pragma unroll 8
    for (int d = 0; d < DDIM; ++d) {
        float v = emb[d * KCODE + k];
        s = fmaf(v, v, s);
    }
    norms[k] = s;
}

// ---------- argmin over codes; writes idx (as float) + histogram ----------
#define TK 128
__global__ __launch_bounds__(256) void vq_argmin(
        const float* __restrict__ x, const float* __restrict__ embT,
        const float* __restrict__ norms, float* __restrict__ idxf,
        int* __restrict__ hist) {
    __shared__ float4 lds4[TK * 16];   // 32 KB: TK codes x 64 floats
    __shared__ float  nlds[TK];
    const int tid = threadIdx.x;
    const int n = blockIdx.x * 256 + tid;

    // x row -> registers (64 VGPRs)
    float4 xr[16];
    const float4* x4 = (const float4*)x + (size_t)n * 16;
    #pragma unroll
    for (int j = 0; j < 16; ++j) xr[j] = x4[j];

    float best = 3.4e38f;
    int   bidx = 0;
    const float4* eT4 = (const float4*)embT;

    for (int t = 0; t < KCODE / TK; ++t) {
        __syncthreads();
        #pragma unroll
        for (int j = 0; j < 8; ++j)
            lds4[tid + j * 256] = eT4[t * (TK * 16) + tid + j * 256];
        if (tid < TK) nlds[tid] = norms[t * TK + tid];
        __syncthreads();

        #pragma unroll 2
        for (int kk = 0; kk < TK; ++kk) {
            float ax = 0.f, ay = 0.f, az = 0.f, aw = 0.f;
            #pragma unroll
            for (int j = 0; j < 16; ++j) {
                float4 e4 = lds4[kk * 16 + j];
                ax = fmaf(xr[j].x, e4.x, ax);
                ay = fmaf(xr[j].y, e4.y, ay);
                az = fmaf(xr[j].z, e4.z, az);
                aw = fmaf(xr[j].w, e4.w, aw);
            }
            float dot  = (ax + ay) + (az + aw);
            float dist = nlds[kk] - 2.0f * dot;   // ||x||^2 dropped: const per pixel
            int kg = t * TK + kk;
            if (dist < best) { best = dist; bidx = kg; }  // strict < => first min wins
        }
    }
    idxf[n] = (float)bidx;
    atomicAdd(&hist[bidx], 1);
}

// ---------- gather quantized + per-block loss partials ----------
__global__ __launch_bounds__(256) void vq_gather_loss(
        const float* __restrict__ x, const float* __restrict__ embT,
        const float* __restrict__ idxf, float* __restrict__ q,
        float* __restrict__ lossp) {
    __shared__ float red[256];
    int i = blockIdx.x * 256 + threadIdx.x;   // over 2097152 float4 units
    int n = i >> 4;
    int j = i & 15;
    int idx = (int)idxf[n];
    float4 e4 = ((const float4*)embT)[idx * 16 + j];
    float4 xv = ((const float4*)x)[i];
    ((float4*)q)[i] = e4;
    float dx = e4.x - xv.x, dy = e4.y - xv.y, dz = e4.z - xv.z, dw = e4.w - xv.w;
    red[threadIdx.x] = dx*dx + dy*dy + dz*dz + dw*dw;
    __syncthreads();
    for (int st = 128; st > 0; st >>= 1) {
        if (threadIdx.x < st) red[threadIdx.x] += red[threadIdx.x + st];
        __syncthreads();
    }
    if (threadIdx.x == 0) lossp[blockIdx.x] = red[0];
}

// ---------- one-hot fill (one block per pixel row; enc only 8B-aligned -> float2) ----------
__global__ void vq_fill(const float* __restrict__ idxf, float* __restrict__ enc) {
    int n = blockIdx.x;
    int idx = (int)idxf[n];
    int k = threadIdx.x * 4;
    float2 v0, v1;
    v0.x = (idx == k    ) ? 1.f : 0.f;
    v0.y = (idx == k + 1) ? 1.f : 0.f;
    v1.x = (idx == k + 2) ? 1.f : 0.f;
    v1.y = (idx == k + 3) ? 1.f : 0.f;
    float2* e2 = (float2*)(enc + (size_t)n * KCODE + k);
    e2[0] = v0;
    e2[1] = v1;
}

// ---------- finalize: loss sum + perplexity ----------
__global__ void vq_final(const float* __restrict__ lossp, const int* __restrict__ hist,
                         float* __restrict__ out_loss, float* __restrict__ out_perp) {
    __shared__ double red[256];
    int tid = threadIdx.x;
    double s = 0.0;
    for (int i = tid; i < 8192; i += 256) s += (double)lossp[i];
    red[tid] = s;
    __syncthreads();
    for (int st = 128; st > 0; st >>= 1) {
        if (tid < st) red[tid] += red[tid + st];
        __syncthreads();
    }
    if (tid == 0)
        *out_loss = (float)((double)BETA * red[0] / (double)((size_t)NPIX * DDIM));
    __syncthreads();

    double e = 0.0;
    for (int i = tid; i < KCODE; i += 256) {
        float p = (float)hist[i] / (float)NPIX;
        e += (double)(p * logf(p + 1e-10f));
    }
    red[tid] = e;
    __syncthreads();
    for (int st = 128; st > 0; st >>= 1) {
        if (tid < st) red[tid] += red[tid + st];
        __syncthreads();
    }
    if (tid == 0) *out_perp = expf((float)(-red[0]));
}

extern "C" void kernel_launch(void* const* d_in, const int* in_sizes, int n_in,
                              void* d_out, int out_size, void* d_ws, size_t ws_size,
                              hipStream_t stream) {
    const float* x   = (const float*)d_in[0];
    const float* emb = (const float*)d_in[1];
    float* out = (float*)d_out;

    char* ws = (char*)d_ws;
    float* lossp = (float*)ws;              // 8192 floats
    int*   hist  = (int*)(ws + 32768);      // 1024 ints
    float* norms = (float*)(ws + 36864);    // 1024 floats
    float* embT  = (float*)(ws + 40960);    // 65536 floats

    float* q       = out + Q_OFF;
    float* o_loss  = out + LOSS_OFF;
    float* o_perp  = out + PERP_OFF;
    float* enc     = out + ENC_OFF;
    float* idxf    = out + IDX_OFF;

    // zero histogram (ws is NOT re-poisoned between replays; we own init)
    hipMemsetAsync(ws + 32768, 0, 4096, stream);

    vq_transpose<<<256, 256, 0, stream>>>(emb, embT);
    vq_norms<<<4, 256, 0, stream>>>(emb, norms);
    vq_argmin<<<NPIX / 256, 256, 0, stream>>>(x, embT, norms, idxf, hist);
    vq_gather_loss<<<8192, 256, 0, stream>>>(x, embT, idxf, q, lossp);
    vq_fill<<<NPIX, 256, 0, stream>>>(idxf, enc);
    vq_final<<<1, 256, 0, stream>>>(lossp, hist, o_loss, o_perp);
}

// Round 2
// 673.309 us; speedup vs baseline: 1.0824x; 1.0824x over previous
//
#include <hip/hip_runtime.h>
#include <math.h>

// Problem constants (x: [32,64,64,64] f32, embedding: [64,1024] f32)
#define NPIX   131072     // 32*64*64
#define DDIM   64
#define KCODE  1024
#define BETA   0.25f

// d_out layout (float32), in reference return order:
//   [0, 8388608)                quantized_st
//   [8388608]                   loss
//   [8388609]                   perplexity
//   [8388610, 142606338)        encodings one-hot  (NOTE: only 8B-aligned!)
//   [142606338, 142737410)      encoding_indices (stored as float values)
#define Q_OFF    0
#define LOSS_OFF 8388608
#define PERP_OFF 8388609
#define ENC_OFF  8388610
#define IDX_OFF  142606338

// ws layout (bytes):
//   [0, 32768)        loss partials float[8192]
//   [32768, 36864)    hist int[1024]          (memset to 0 each call)
//   [36864, 40960)    norms float[1024]
//   [40960, 303104)   embT float[1024*64]     (embT[k][d] = emb[d][k])

typedef float f32x4 __attribute__((ext_vector_type(4)));

// ---------- transpose embedding [D][K] -> [K][D] ----------
__global__ void vq_transpose(const float* __restrict__ emb, float* __restrict__ embT) {
    int i = blockIdx.x * 256 + threadIdx.x;   // over 65536
    int d = i >> 10;
    int k = i & 1023;
    embT[k * DDIM + d] = emb[i];
}

// ---------- per-code squared norms ----------
__global__ void vq_norms(const float* __restrict__ emb, float* __restrict__ norms) {
    int k = blockIdx.x * 256 + threadIdx.x;   // over 1024
    float s = 0.f;
    #pragma unroll 8
    for (int d = 0; d < DDIM; ++d) {
        float v = emb[d * KCODE + k];
        s = fmaf(v, v, s);
    }
    norms[k] = s;
}

// ---------- argmin over a K-half via scalar-memory (SMEM) embedding loads ----
// e-row address is wave-uniform -> s_load_dwordx4 into SGPRs; v_fmac uses the
// SGPR operand directly. No LDS at all. blockIdx.y selects K-half (occupancy:
// 4096 waves = 4/SIMD instead of 2/SIMD).
__global__ __launch_bounds__(256) void vq_argmin_half(
        const float* __restrict__ x, const float* __restrict__ embT,
        const float* __restrict__ norms, float2* __restrict__ cand) {
    const int half = blockIdx.y;                  // 0 or 1
    const int n = blockIdx.x * 256 + threadIdx.x;
    const int k0 = half * (KCODE / 2);

    // x row -> 64 VGPRs
    f32x4 xr[16];
    const f32x4* x4 = (const f32x4*)x + (size_t)n * 16;
    #pragma unroll
    for (int j = 0; j < 16; ++j) xr[j] = x4[j];

    float best = 3.4e38f;
    int   bidx = k0;
    const float* pbase = embT + (size_t)k0 * DDIM;

    #pragma unroll 1
    for (int kk = 0; kk < KCODE / 2; ++kk) {
        f32x4 e[16];
        const float* p = pbase + kk * DDIM;       // wave-uniform address
        asm volatile(
            "s_load_dwordx4 %0, %16, 0x0\n\t"
            "s_load_dwordx4 %1, %16, 0x10\n\t"
            "s_load_dwordx4 %2, %16, 0x20\n\t"
            "s_load_dwordx4 %3, %16, 0x30\n\t"
            "s_load_dwordx4 %4, %16, 0x40\n\t"
            "s_load_dwordx4 %5, %16, 0x50\n\t"
            "s_load_dwordx4 %6, %16, 0x60\n\t"
            "s_load_dwordx4 %7, %16, 0x70\n\t"
            "s_load_dwordx4 %8, %16, 0x80\n\t"
            "s_load_dwordx4 %9, %16, 0x90\n\t"
            "s_load_dwordx4 %10, %16, 0xa0\n\t"
            "s_load_dwordx4 %11, %16, 0xb0\n\t"
            "s_load_dwordx4 %12, %16, 0xc0\n\t"
            "s_load_dwordx4 %13, %16, 0xd0\n\t"
            "s_load_dwordx4 %14, %16, 0xe0\n\t"
            "s_load_dwordx4 %15, %16, 0xf0\n\t"
            "s_waitcnt lgkmcnt(0)"
            : "=&s"(e[0]),  "=&s"(e[1]),  "=&s"(e[2]),  "=&s"(e[3]),
              "=&s"(e[4]),  "=&s"(e[5]),  "=&s"(e[6]),  "=&s"(e[7]),
              "=&s"(e[8]),  "=&s"(e[9]),  "=&s"(e[10]), "=&s"(e[11]),
              "=&s"(e[12]), "=&s"(e[13]), "=&s"(e[14]), "=&s"(e[15])
            : "s"(p));

        float a0 = 0.f, a1 = 0.f, a2 = 0.f, a3 = 0.f;
        #pragma unroll
        for (int j = 0; j < 16; ++j) {
            a0 = fmaf(xr[j].x, e[j].x, a0);
            a1 = fmaf(xr[j].y, e[j].y, a1);
            a2 = fmaf(xr[j].z, e[j].z, a2);
            a3 = fmaf(xr[j].w, e[j].w, a3);
        }
        float dot  = (a0 + a1) + (a2 + a3);
        float dist = fmaf(-2.0f, dot, norms[k0 + kk]);   // ||x||^2 dropped: const per pixel
        int kg = k0 + kk;
        if (dist < best) { best = dist; bidx = kg; }     // strict < => first min wins
    }
    cand[(size_t)half * NPIX + n] = make_float2(best, (float)bidx);
}

// ---------- merge the two K-half candidates (first-min-wins) ----------
__global__ void vq_combine(const float2* __restrict__ cand, float* __restrict__ idxf,
                           int* __restrict__ hist) {
    int n = blockIdx.x * 256 + threadIdx.x;
    float2 c0 = cand[n];
    float2 c1 = cand[NPIX + n];
    // half 0 holds the lower indices: <= keeps the earlier index on exact tie
    int idx = (c0.x <= c1.x) ? (int)c0.y : (int)c1.y;
    idxf[n] = (float)idx;
    atomicAdd(&hist[idx], 1);
}

// ---------- gather quantized + per-block loss partials ----------
__global__ __launch_bounds__(256) void vq_gather_loss(
        const float* __restrict__ x, const float* __restrict__ embT,
        const float* __restrict__ idxf, float* __restrict__ q,
        float* __restrict__ lossp) {
    __shared__ float red[256];
    int i = blockIdx.x * 256 + threadIdx.x;   // over 2097152 float4 units
    int n = i >> 4;
    int j = i & 15;
    int idx = (int)idxf[n];
    float4 e4 = ((const float4*)embT)[idx * 16 + j];
    float4 xv = ((const float4*)x)[i];
    ((float4*)q)[i] = e4;
    float dx = e4.x - xv.x, dy = e4.y - xv.y, dz = e4.z - xv.z, dw = e4.w - xv.w;
    red[threadIdx.x] = dx*dx + dy*dy + dz*dz + dw*dw;
    __syncthreads();
    for (int st = 128; st > 0; st >>= 1) {
        if (threadIdx.x < st) red[threadIdx.x] += red[threadIdx.x + st];
        __syncthreads();
    }
    if (threadIdx.x == 0) lossp[blockIdx.x] = red[0];
}

// ---------- one-hot fill (one block per pixel row; enc only 8B-aligned -> float2) ----------
__global__ void vq_fill(const float* __restrict__ idxf, float* __restrict__ enc) {
    int n = blockIdx.x;
    int idx = (int)idxf[n];
    int k = threadIdx.x * 4;
    float2 v0, v1;
    v0.x = (idx == k    ) ? 1.f : 0.f;
    v0.y = (idx == k + 1) ? 1.f : 0.f;
    v1.x = (idx == k + 2) ? 1.f : 0.f;
    v1.y = (idx == k + 3) ? 1.f : 0.f;
    float2* e2 = (float2*)(enc + (size_t)n * KCODE + k);
    e2[0] = v0;
    e2[1] = v1;
}

// ---------- finalize: loss sum + perplexity ----------
__global__ void vq_final(const float* __restrict__ lossp, const int* __restrict__ hist,
                         float* __restrict__ out_loss, float* __restrict__ out_perp) {
    __shared__ double red[256];
    int tid = threadIdx.x;
    double s = 0.0;
    for (int i = tid; i < 8192; i += 256) s += (double)lossp[i];
    red[tid] = s;
    __syncthreads();
    for (int st = 128; st > 0; st >>= 1) {
        if (tid < st) red[tid] += red[tid + st];
        __syncthreads();
    }
    if (tid == 0)
        *out_loss = (float)((double)BETA * red[0] / (double)((size_t)NPIX * DDIM));
    __syncthreads();

    double e = 0.0;
    for (int i = tid; i < KCODE; i += 256) {
        float p = (float)hist[i] / (float)NPIX;
        e += (double)(p * logf(p + 1e-10f));
    }
    red[tid] = e;
    __syncthreads();
    for (int st = 128; st > 0; st >>= 1) {
        if (tid < st) red[tid] += red[tid + st];
        __syncthreads();
    }
    if (tid == 0) *out_perp = expf((float)(-red[0]));
}

extern "C" void kernel_launch(void* const* d_in, const int* in_sizes, int n_in,
                              void* d_out, int out_size, void* d_ws, size_t ws_size,
                              hipStream_t stream) {
    const float* x   = (const float*)d_in[0];
    const float* emb = (const float*)d_in[1];
    float* out = (float*)d_out;

    char* ws = (char*)d_ws;
    float* lossp = (float*)ws;              // 8192 floats
    int*   hist  = (int*)(ws + 32768);      // 1024 ints
    float* norms = (float*)(ws + 36864);    // 1024 floats
    float* embT  = (float*)(ws + 40960);    // 65536 floats

    float* q       = out + Q_OFF;
    float* o_loss  = out + LOSS_OFF;
    float* o_perp  = out + PERP_OFF;
    float* enc     = out + ENC_OFF;
    float* idxf    = out + IDX_OFF;

    // candidate (dist, idx) pairs parked at the head of the enc region;
    // vq_fill fully overwrites it afterwards (2 MB used of 536 MB).
    float2* cand = (float2*)enc;

    // zero histogram (ws is NOT re-poisoned between replays; we own init)
    hipMemsetAsync(ws + 32768, 0, 4096, stream);

    vq_transpose<<<256, 256, 0, stream>>>(emb, embT);
    vq_norms<<<4, 256, 0, stream>>>(emb, norms);
    vq_argmin_half<<<dim3(NPIX / 256, 2), 256, 0, stream>>>(x, embT, norms, cand);
    vq_combine<<<NPIX / 256, 256, 0, stream>>>(cand, idxf, hist);
    vq_gather_loss<<<8192, 256, 0, stream>>>(x, embT, idxf, q, lossp);
    vq_fill<<<NPIX, 256, 0, stream>>>(idxf, enc);
    vq_final<<<1, 256, 0, stream>>>(lossp, hist, o_loss, o_perp);
}

// Round 3
// 273.739 us; speedup vs baseline: 2.6624x; 2.4597x over previous
//
#include <hip/hip_runtime.h>
#include <hip/hip_fp16.h>
#include <math.h>

// Problem constants (x: [32,64,64,64] f32, embedding: [64,1024] f32)
#define NPIX   131072
#define DDIM   64
#define KCODE  1024
#define BETA   0.25f
#define EPS2   4e-3f      // top-2 gap threshold triggering exact fp32 fix-up
#define FIXCAP 2048

// d_out layout (float32), in reference return order:
#define Q_OFF    0
#define LOSS_OFF 8388608
#define PERP_OFF 8388609
#define ENC_OFF  8388610   // NOTE: byte base ≡ 8 (mod 16) -> float2 align only
#define IDX_OFF  142606338

// scratch parked inside the enc region (float offsets from enc base); all of
// it is overwritten by vq_fill afterwards. Offsets chosen so 16B-aligned
// regions land on byte ≡ 8 (mod 16) offsets (enc base ≡ 8 mod 16).
#define CAND_F     0          // float2[2][8*NPIX]-style candidate entries (16 MB)
#define EHT_F      4194306    // f16[1024][64] hi   (byte off ≡ 8 -> abs ≡ 0 mod 16)
#define ELT_F      4227078    // f16[1024][64] lo
#define FIXLIST_I  4259848    // int[FIXCAP]
#define FIXCOUNT_I 4261896    // int

// ws layout (bytes) — same footprint as the proven round-1/2 kernels:
//   [0,32768) loss partials f32[8192]; [32768,36864) hist int[1024];
//   [36864,40960) norms f32[1024];     [40960,303104) embT f32[1024][64]

typedef _Float16 half8 __attribute__((ext_vector_type(8)));
typedef float    f32x4 __attribute__((ext_vector_type(4)));

// ---------- prep: transpose to embT, f16 hi/lo split ----------
__global__ void vq_prep(const float* __restrict__ emb, float* __restrict__ embT,
                        __half* __restrict__ eh, __half* __restrict__ el) {
    int i = blockIdx.x * 256 + threadIdx.x;   // over 65536
    int d = i >> 10;
    int k = i & 1023;
    float v = emb[i];
    embT[k * DDIM + d] = v;
    _Float16 h = (_Float16)v;
    _Float16 l = (_Float16)(v - (float)h);
    ((_Float16*)eh)[k * DDIM + d] = h;
    ((_Float16*)el)[k * DDIM + d] = l;
}

__global__ void vq_norms(const float* __restrict__ emb, float* __restrict__ norms) {
    int k = blockIdx.x * 256 + threadIdx.x;   // over 1024
    float s = 0.f;
    #pragma unroll 8
    for (int d = 0; d < DDIM; ++d) {
        float v = emb[d * KCODE + k];
        s = fmaf(v, v, s);
    }
    norms[k] = s;
}

// ---------- MFMA argmin: block = 4 waves x 32 pixels, 128-code panel ----------
// dist = ||e||^2 - 2 x.e (||x||^2 const per pixel). dot via 3 f16-split MFMAs.
// Per pixel: track (b1, i1, b2); gap < EPS2 -> exact fix-up later.
__global__ __launch_bounds__(256) void vq_argmin_mfma(
        const float* __restrict__ x, const __half* __restrict__ eh,
        const __half* __restrict__ el, const float* __restrict__ norms,
        float2* __restrict__ cand) {
    __shared__ char lds_raw[33280];
    half8* EH8 = (half8*)lds_raw;              // [128 codes][8 granules] swizzled
    half8* EL8 = (half8*)(lds_raw + 16384);
    float* NRM = (float*)(lds_raw + 32768);    // [128]

    const int tid   = threadIdx.x;
    const int kbase = blockIdx.y * 128;

    // stage e panels with XOR granule swizzle (granule g -> g ^ (code&7))
    {
        const float4* sh = (const float4*)(eh + (size_t)kbase * DDIM);
        const float4* sl = (const float4*)(el + (size_t)kbase * DDIM);
        float4* dh = (float4*)EH8;
        float4* dl = (float4*)EL8;
        #pragma unroll
        for (int i = 0; i < 4; ++i) {
            int G = tid + i * 256;            // 0..1023 granules of 16B
            int code = G >> 3, g = G & 7;
            int sw = g ^ (code & 7);
            dh[code * 8 + sw] = sh[G];
            dl[code * 8 + sw] = sl[G];
        }
        if (tid < 128) NRM[tid] = norms[kbase + tid];
    }
    __syncthreads();

    const int wave = tid >> 6;
    const int lane = tid & 63;
    const int lx = lane & 15;   // B col / A row
    const int lk = lane >> 4;   // k-group
    const int pixbase = blockIdx.x * 128 + wave * 32;

    // A fragments (x rows), reused across all 8 chunks:
    // lane holds x[pixbase + mt*16 + lx][lk*8 + kh*32 .. +8)
    half8 ah[2][2], al[2][2];
    #pragma unroll
    for (int mt = 0; mt < 2; ++mt) {
        const float* xr = x + (size_t)(pixbase + mt * 16 + lx) * DDIM + lk * 8;
        #pragma unroll
        for (int kh = 0; kh < 2; ++kh) {
            float4 v0 = *(const float4*)(xr + kh * 32);
            float4 v1 = *(const float4*)(xr + kh * 32 + 4);
            half8 hh, ll;
            float vv;
            vv = v0.x; hh[0] = (_Float16)vv; ll[0] = (_Float16)(vv - (float)hh[0]);
            vv = v0.y; hh[1] = (_Float16)vv; ll[1] = (_Float16)(vv - (float)hh[1]);
            vv = v0.z; hh[2] = (_Float16)vv; ll[2] = (_Float16)(vv - (float)hh[2]);
            vv = v0.w; hh[3] = (_Float16)vv; ll[3] = (_Float16)(vv - (float)hh[3]);
            vv = v1.x; hh[4] = (_Float16)vv; ll[4] = (_Float16)(vv - (float)hh[4]);
            vv = v1.y; hh[5] = (_Float16)vv; ll[5] = (_Float16)(vv - (float)hh[5]);
            vv = v1.z; hh[6] = (_Float16)vv; ll[6] = (_Float16)(vv - (float)hh[6]);
            vv = v1.w; hh[7] = (_Float16)vv; ll[7] = (_Float16)(vv - (float)hh[7]);
            ah[mt][kh] = hh;
            al[mt][kh] = ll;
        }
    }

    // running top-2 per slot (mt, r): pixel p_local = mt*16 + lk*4 + r
    float b1[2][4], b2[2][4];
    int   i1[2][4];
    #pragma unroll
    for (int mt = 0; mt < 2; ++mt)
        #pragma unroll
        for (int r = 0; r < 4; ++r) { b1[mt][r] = 3.4e38f; b2[mt][r] = 3.4e38f; i1[mt][r] = 0; }

    #pragma unroll 1
    for (int c = 0; c < 8; ++c) {
        int code = c * 16 + lx;
        const half8* bh = EH8 + code * 8;
        const half8* bl = EL8 + code * 8;
        int sw0 = lk ^ (code & 7);
        int sw1 = (lk + 4) ^ (code & 7);
        half8 bh0 = bh[sw0], bh1 = bh[sw1];
        half8 bl0 = bl[sw0], bl1 = bl[sw1];

        f32x4 acc0 = {0.f, 0.f, 0.f, 0.f};
        f32x4 acc1 = {0.f, 0.f, 0.f, 0.f};
        acc0 = __builtin_amdgcn_mfma_f32_16x16x32_f16(ah[0][0], bh0, acc0, 0, 0, 0);
        acc1 = __builtin_amdgcn_mfma_f32_16x16x32_f16(ah[1][0], bh0, acc1, 0, 0, 0);
        acc0 = __builtin_amdgcn_mfma_f32_16x16x32_f16(ah[0][1], bh1, acc0, 0, 0, 0);
        acc1 = __builtin_amdgcn_mfma_f32_16x16x32_f16(ah[1][1], bh1, acc1, 0, 0, 0);
        acc0 = __builtin_amdgcn_mfma_f32_16x16x32_f16(ah[0][0], bl0, acc0, 0, 0, 0);
        acc1 = __builtin_amdgcn_mfma_f32_16x16x32_f16(ah[1][0], bl0, acc1, 0, 0, 0);
        acc0 = __builtin_amdgcn_mfma_f32_16x16x32_f16(ah[0][1], bl1, acc0, 0, 0, 0);
        acc1 = __builtin_amdgcn_mfma_f32_16x16x32_f16(ah[1][1], bl1, acc1, 0, 0, 0);
        acc0 = __builtin_amdgcn_mfma_f32_16x16x32_f16(al[0][0], bh0, acc0, 0, 0, 0);
        acc1 = __builtin_amdgcn_mfma_f32_16x16x32_f16(al[1][0], bh0, acc1, 0, 0, 0);
        acc0 = __builtin_amdgcn_mfma_f32_16x16x32_f16(al[0][1], bh1, acc0, 0, 0, 0);
        acc1 = __builtin_amdgcn_mfma_f32_16x16x32_f16(al[1][1], bh1, acc1, 0, 0, 0);

        float nrm = NRM[c * 16 + lx];
        int codeg = kbase + c * 16 + lx;
        #pragma unroll
        for (int r = 0; r < 4; ++r) {
            // C layout [m89]: col = lane&15 (code), row = (lane>>4)*4 + r (pixel)
            float d0 = fmaf(-2.0f, acc0[r], nrm);
            bool lt0 = d0 < b1[0][r];
            b2[0][r] = fminf(b2[0][r], fmaxf(b1[0][r], d0));
            b1[0][r] = fminf(b1[0][r], d0);
            i1[0][r] = lt0 ? codeg : i1[0][r];
            float d1 = fmaf(-2.0f, acc1[r], nrm);
            bool lt1 = d1 < b1[1][r];
            b2[1][r] = fminf(b2[1][r], fmaxf(b1[1][r], d1));
            b1[1][r] = fminf(b1[1][r], d1);
            i1[1][r] = lt1 ? codeg : i1[1][r];
        }
    }

    // cross-lane per-pixel top-2 merge via LDS scratch (panels now dead)
    __syncthreads();
    float* S  = (float*)(lds_raw + wave * 6528);  // 3 planes of [32][17] floats
    float* SB1 = S, *SI = S + 544, *SB2 = S + 1088;
    #pragma unroll
    for (int mt = 0; mt < 2; ++mt)
        #pragma unroll
        for (int r = 0; r < 4; ++r) {
            int p = mt * 16 + lk * 4 + r;
            SB1[p * 17 + lx] = b1[mt][r];
            SI [p * 17 + lx] = (float)i1[mt][r];
            SB2[p * 17 + lx] = b2[mt][r];
        }
    __syncthreads();

    if (lane < 32) {
        float gb1 = 3.4e38f, gb2 = 3.4e38f;
        int gi1 = KCODE;
        #pragma unroll
        for (int j = 0; j < 16; ++j) {
            float cb1 = SB1[lane * 17 + j];
            int   ci1 = (int)SI[lane * 17 + j];
            float cb2 = SB2[lane * 17 + j];
            if (cb1 < gb1 || (cb1 == gb1 && ci1 < gi1)) {
                gb2 = fminf(gb1, cb2); gb1 = cb1; gi1 = ci1;
            } else {
                gb2 = fminf(gb2, cb1);
            }
        }
        int pixel = blockIdx.x * 128 + wave * 32 + lane;
        size_t e = ((size_t)blockIdx.y * NPIX + pixel) * 2;
        cand[e]     = make_float2(gb1, (float)gi1);
        cand[e + 1] = make_float2(gb2, 0.f);
    }
}

// ---------- merge 8 split candidates; flag near-ties for exact fix-up ----------
__global__ void vq_combine8(const float2* __restrict__ cand, float* __restrict__ idxf,
                            int* __restrict__ fixlist, int* __restrict__ fixcount) {
    int n = blockIdx.x * 256 + threadIdx.x;
    float gb1 = 3.4e38f, gb2 = 3.4e38f;
    int gi1 = 0;
    #pragma unroll
    for (int s = 0; s < 8; ++s) {          // ascending s = ascending code range
        size_t e = ((size_t)s * NPIX + n) * 2;
        float2 A = cand[e];
        float2 B = cand[e + 1];
        float cb1 = A.x, cb2 = B.x;
        int ci1 = (int)A.y;
        if (cb1 < gb1) { gb2 = fminf(gb1, cb2); gb1 = cb1; gi1 = ci1; }
        else           { gb2 = fminf(gb2, cb1); }
    }
    idxf[n] = (float)gi1;
    if (gb2 - gb1 < EPS2) {
        int slot = atomicAdd(fixcount, 1);
        if (slot < FIXCAP) fixlist[slot] = n;
    }
}

// ---------- exact fp32 rescan for flagged pixels (first-min-wins) ----------
__global__ __launch_bounds__(64) void vq_fixup(
        const float* __restrict__ x, const float* __restrict__ embT,
        const float* __restrict__ norms, const int* __restrict__ fixlist,
        const int* __restrict__ fixcount, float* __restrict__ idxf) {
    int b = blockIdx.x;
    int cnt = *fixcount;
    if (b >= cnt) return;
    int pixel = fixlist[b];
    int lane = threadIdx.x;

    float xr[64];
    const float4* x4 = (const float4*)(x + (size_t)pixel * DDIM);
    #pragma unroll
    for (int j = 0; j < 16; ++j) {
        float4 v = x4[j];
        xr[j * 4] = v.x; xr[j * 4 + 1] = v.y; xr[j * 4 + 2] = v.z; xr[j * 4 + 3] = v.w;
    }
    float bd = 3.4e38f;
    int bi = 0;
    #pragma unroll 1
    for (int c = 0; c < 16; ++c) {
        int k = lane * 16 + c;               // per-lane ascending idx
        const float4* e4 = (const float4*)(embT + (size_t)k * DDIM);
        float a0 = 0.f, a1 = 0.f, a2 = 0.f, a3 = 0.f;
        #pragma unroll
        for (int j = 0; j < 16; ++j) {
            float4 ev = e4[j];
            a0 = fmaf(xr[j * 4],     ev.x, a0);
            a1 = fmaf(xr[j * 4 + 1], ev.y, a1);
            a2 = fmaf(xr[j * 4 + 2], ev.z, a2);
            a3 = fmaf(xr[j * 4 + 3], ev.w, a3);
        }
        float dd = fmaf(-2.0f, (a0 + a1) + (a2 + a3), norms[k]);
        if (dd < bd) { bd = dd; bi = k; }
    }
    #pragma unroll
    for (int m = 1; m < 64; m <<= 1) {       // lex-min (dist, idx) across 64 lanes
        float od = __shfl_xor(bd, m, 64);
        int   oi = __shfl_xor(bi, m, 64);
        if (od < bd || (od == bd && oi < bi)) { bd = od; bi = oi; }
    }
    if (lane == 0) idxf[pixel] = (float)bi;
}

// ---------- gather quantized + per-block loss partials ----------
__global__ __launch_bounds__(256) void vq_gather_loss(
        const float* __restrict__ x, const float* __restrict__ embT,
        const float* __restrict__ idxf, float* __restrict__ q,
        float* __restrict__ lossp) {
    __shared__ float red[256];
    int i = blockIdx.x * 256 + threadIdx.x;   // over 2097152 float4 units
    int n = i >> 4;
    int j = i & 15;
    int idx = (int)idxf[n];
    float4 e4 = ((const float4*)embT)[idx * 16 + j];
    float4 xv = ((const float4*)x)[i];
    ((float4*)q)[i] = e4;
    float dx = e4.x - xv.x, dy = e4.y - xv.y, dz = e4.z - xv.z, dw = e4.w - xv.w;
    red[threadIdx.x] = dx*dx + dy*dy + dz*dz + dw*dw;
    __syncthreads();
    for (int st = 128; st > 0; st >>= 1) {
        if (threadIdx.x < st) red[threadIdx.x] += red[threadIdx.x + st];
        __syncthreads();
    }
    if (threadIdx.x == 0) lossp[blockIdx.x] = red[0];
}

// ---------- one-hot fill + histogram ----------
__global__ void vq_fill(const float* __restrict__ idxf, float* __restrict__ enc,
                        int* __restrict__ hist) {
    int n = blockIdx.x;
    int idx = (int)idxf[n];
    if (threadIdx.x == 0) atomicAdd(&hist[idx], 1);
    int k = threadIdx.x * 4;
    float2 v0, v1;
    v0.x = (idx == k    ) ? 1.f : 0.f;
    v0.y = (idx == k + 1) ? 1.f : 0.f;
    v1.x = (idx == k + 2) ? 1.f : 0.f;
    v1.y = (idx == k + 3) ? 1.f : 0.f;
    float2* e2 = (float2*)(enc + (size_t)n * KCODE + k);
    e2[0] = v0;
    e2[1] = v1;
}

// ---------- finalize: loss sum + perplexity ----------
__global__ void vq_final(const float* __restrict__ lossp, const int* __restrict__ hist,
                         float* __restrict__ out_loss, float* __restrict__ out_perp) {
    __shared__ double red[256];
    int tid = threadIdx.x;
    double s = 0.0;
    for (int i = tid; i < 8192; i += 256) s += (double)lossp[i];
    red[tid] = s;
    __syncthreads();
    for (int st = 128; st > 0; st >>= 1) {
        if (tid < st) red[tid] += red[tid + st];
        __syncthreads();
    }
    if (tid == 0)
        *out_loss = (float)((double)BETA * red[0] / (double)((size_t)NPIX * DDIM));
    __syncthreads();

    double e = 0.0;
    for (int i = tid; i < KCODE; i += 256) {
        float p = (float)hist[i] / (float)NPIX;
        e += (double)(p * logf(p + 1e-10f));
    }
    red[tid] = e;
    __syncthreads();
    for (int st = 128; st > 0; st >>= 1) {
        if (tid < st) red[tid] += red[tid + st];
        __syncthreads();
    }
    if (tid == 0) *out_perp = expf((float)(-red[0]));
}

extern "C" void kernel_launch(void* const* d_in, const int* in_sizes, int n_in,
                              void* d_out, int out_size, void* d_ws, size_t ws_size,
                              hipStream_t stream) {
    const float* x   = (const float*)d_in[0];
    const float* emb = (const float*)d_in[1];
    float* out = (float*)d_out;

    char* ws = (char*)d_ws;
    float* lossp = (float*)ws;              // 8192 floats
    int*   hist  = (int*)(ws + 32768);      // 1024 ints
    float* norms = (float*)(ws + 36864);    // 1024 floats
    float* embT  = (float*)(ws + 40960);    // 65536 floats

    float* q      = out + Q_OFF;
    float* o_loss = out + LOSS_OFF;
    float* o_perp = out + PERP_OFF;
    float* enc    = out + ENC_OFF;
    float* idxf   = out + IDX_OFF;

    // scratch inside the enc region (fully overwritten by vq_fill afterwards)
    float2* cand   = (float2*)(enc + CAND_F);
    __half* eh     = (__half*)(enc + EHT_F);
    __half* el     = (__half*)(enc + ELT_F);
    int* fixlist   = (int*)(enc + FIXLIST_I);
    int* fixcount  = (int*)(enc + FIXCOUNT_I);

    hipMemsetAsync(ws + 32768, 0, 4096, stream);          // hist
    hipMemsetAsync((void*)fixcount, 0, 4, stream);        // fix-up counter

    vq_prep<<<256, 256, 0, stream>>>(emb, embT, eh, el);
    vq_norms<<<4, 256, 0, stream>>>(emb, norms);
    vq_argmin_mfma<<<dim3(NPIX / 128, 8), 256, 0, stream>>>(x, eh, el, norms, cand);
    vq_combine8<<<NPIX / 256, 256, 0, stream>>>(cand, idxf, fixlist, fixcount);
    vq_fixup<<<FIXCAP, 64, 0, stream>>>(x, embT, norms, fixlist, fixcount, idxf);
    vq_gather_loss<<<8192, 256, 0, stream>>>(x, embT, idxf, q, lossp);
    vq_fill<<<NPIX, 256, 0, stream>>>(idxf, enc, hist);
    vq_final<<<1, 256, 0, stream>>>(lossp, hist, o_loss, o_perp);
}